// Round 11
// baseline (197.794 us; speedup 1.0000x reference)
//
#include <hip/hip_runtime.h>
#include <math.h>

// Round 11:
//  - gemm_outp retiled 64x128 (grid 6x128 = 768 = exactly 3 blocks/CU; old
//    128x128 grid was 384 = 1.5/CU -> half the CUs ran 2 serial tiles).
//  - flash: T-loop unrolled x2 with PARITY-INDEXED P strips (compile-time
//    Ps[p]) -> iteration T+1's ds_writes no longer alias T's ds_reads, so
//    softmax(T+1) can overlap PV(T)'s LDS tail.
//  - gemm_qkv (z-fused) and cast unchanged from R10.

typedef __bf16 bf16x8 __attribute__((ext_vector_type(8)));
typedef float  f32x4  __attribute__((ext_vector_type(4)));
typedef unsigned u32x2 __attribute__((ext_vector_type(2)));
typedef unsigned u32x4 __attribute__((ext_vector_type(4)));
typedef unsigned short ushort_t;

__device__ __forceinline__ unsigned short f2bf(float f) {
    unsigned u = __float_as_uint(f);
    u += 0x7fffu + ((u >> 16) & 1u);          // round-to-nearest-even
    return (unsigned short)(u >> 16);
}
__device__ __forceinline__ unsigned pk16(unsigned short lo, unsigned short hi) {
    return (unsigned)lo | ((unsigned)hi << 16);
}

#define GLL16(g, l)                                                                        \
    __builtin_amdgcn_global_load_lds((const __attribute__((address_space(1))) void*)(g),   \
                                     (__attribute__((address_space(3))) void*)(l), 16, 0, 0)

// ---------------------------------------------------------------------------
// cast fp32 -> bf16: y=0 -> x, y=1..4 -> Wq,Wk,Wv,Wo
// ---------------------------------------------------------------------------
__global__ __launch_bounds__(256)
void cast_all(const float* __restrict__ x,
              const float* __restrict__ w0, const float* __restrict__ w1,
              const float* __restrict__ w2, const float* __restrict__ w3,
              ushort_t* __restrict__ xb, ushort_t* __restrict__ wb0,
              ushort_t* __restrict__ wb1, ushort_t* __restrict__ wb2,
              ushort_t* __restrict__ wb3)
{
    const int y = blockIdx.y;
    const float* s; ushort_t* d; int n;
    switch (y) {
        case 0:  s = x;  d = xb;  n = 8192 * 768; break;
        case 1:  s = w0; d = wb0; n = 768 * 768;  break;
        case 2:  s = w1; d = wb1; n = 768 * 768;  break;
        case 3:  s = w2; d = wb2; n = 768 * 768;  break;
        default: s = w3; d = wb3; n = 768 * 768;  break;
    }
    const int i = (blockIdx.x * 256 + threadIdx.x) * 8;
    if (i >= n) return;
    const float4 f0 = *(const float4*)(s + i);
    const float4 f1 = *(const float4*)(s + i + 4);
    ushort4 p0, p1;
    p0.x = f2bf(f0.x); p0.y = f2bf(f0.y); p0.z = f2bf(f0.z); p0.w = f2bf(f0.w);
    p1.x = f2bf(f1.x); p1.y = f2bf(f1.y); p1.z = f2bf(f1.z); p1.w = f2bf(f1.w);
    *(ushort4*)(d + i)     = p0;
    *(ushort4*)(d + i + 4) = p1;
}

// ---------------------------------------------------------------------------
// Z-fused QKV GEMM (R10). Block = 64m x 128n, 4 waves (64x32 each per z).
// ---------------------------------------------------------------------------
__global__ __launch_bounds__(256, 3)
void gemm_qkv(const ushort_t* __restrict__ xb,
              const ushort_t* __restrict__ wqb, const ushort_t* __restrict__ wkb,
              const ushort_t* __restrict__ wvb,
              const float* __restrict__ bq, const float* __restrict__ bk,
              const float* __restrict__ bv,
              ushort_t* __restrict__ Qh, ushort_t* __restrict__ Kl,
              ushort_t* __restrict__ Vl)
{
    __shared__ ushort_t smem[14336];     // As 2048 | Ws0,Ws1,Ws2 4096 each
    ushort_t* As  = smem;
    ushort_t* Ws0 = smem + 2048;
    ushort_t* Ws1 = smem + 6144;
    ushort_t* Ws2 = smem + 10240;

    const int tid = threadIdx.x, L = tid & 63, wv = tid >> 6;
    const int c = L & 15, g = L >> 4;
    const int n0 = blockIdx.x * 128, m0 = blockIdx.y * 64;

    const int qs = ((tid & 3) ^ ((tid >> 3) & 3)) * 8;   // swizzled k-chunk
    const ushort_t* ap = xb  + (size_t)(m0 + (tid >> 2)) * 768 + qs;
    const ushort_t* wq = wqb + (size_t)(n0 + (tid >> 2)) * 768 + qs;
    const ushort_t* wk = wkb + (size_t)(n0 + (tid >> 2)) * 768 + qs;
    const ushort_t* wvp = wvb + (size_t)(n0 + (tid >> 2)) * 768 + qs;
    const size_t st64 = (size_t)64 * 768;
    const int sg = (g ^ ((c >> 1) & 3)) * 8;             // swizzled read col

    f32x4 acc[3][4][2];
#pragma unroll
    for (int z = 0; z < 3; ++z)
#pragma unroll
        for (int i = 0; i < 4; ++i)
#pragma unroll
            for (int j = 0; j < 2; ++j) acc[z][i][j] = (f32x4){0.f, 0.f, 0.f, 0.f};

    for (int k0 = 0; k0 < 768; k0 += 32) {
        __syncthreads();
        GLL16(ap + k0,          &As[(size_t)tid * 8]);
        GLL16(wq + k0,          &Ws0[(size_t)tid * 8]);
        GLL16(wq + st64 + k0,   &Ws0[(size_t)(tid + 256) * 8]);
        GLL16(wk + k0,          &Ws1[(size_t)tid * 8]);
        GLL16(wk + st64 + k0,   &Ws1[(size_t)(tid + 256) * 8]);
        GLL16(wvp + k0,         &Ws2[(size_t)tid * 8]);
        GLL16(wvp + st64 + k0,  &Ws2[(size_t)(tid + 256) * 8]);
        __syncthreads();
        bf16x8 af[4];
#pragma unroll
        for (int i = 0; i < 4; ++i)
            af[i] = *(const bf16x8*)&As[(i * 16 + c) * 32 + sg];
        bf16x8 bf[3][2];
        const ushort_t* wsz[3] = {Ws0, Ws1, Ws2};
#pragma unroll
        for (int z = 0; z < 3; ++z)
#pragma unroll
            for (int j = 0; j < 2; ++j)
                bf[z][j] = *(const bf16x8*)&wsz[z][(wv * 32 + j * 16 + c) * 32 + sg];
#pragma unroll
        for (int z = 0; z < 3; ++z)
#pragma unroll
            for (int i = 0; i < 4; ++i)
#pragma unroll
                for (int j = 0; j < 2; ++j)
                    acc[z][i][j] = __builtin_amdgcn_mfma_f32_16x16x32_bf16(
                        af[i], bf[z][j], acc[z][i][j], 0, 0, 0);
    }

    // ---------------- epilogues (per-wave private strips) ----------------
    const int b  = m0 >> 10, nb = m0 & 1023;
    const int hcol = n0 + wv * 32;
    const int h = hcol >> 6, uh = (hcol >> 5) & 1;
    const int bh = b * 12 + h;
    ushort_t* scr = smem + wv * 2304;

    float bias2[3][2];
#pragma unroll
    for (int j = 0; j < 2; ++j) {
        bias2[0][j] = bq[hcol + j * 16 + c];
        bias2[1][j] = bk[hcol + j * 16 + c];
        bias2[2][j] = bv[hcol + j * 16 + c];
    }

    __syncthreads();   // staging LDS -> scratch

    // z=0: Q plain [bh][token][hd64]; token-major strip [64][36]
#pragma unroll
    for (int i = 0; i < 4; ++i)
#pragma unroll
        for (int j = 0; j < 2; ++j)
#pragma unroll
            for (int r = 0; r < 4; ++r)
                scr[(i * 16 + g * 4 + r) * 36 + j * 16 + c] =
                    f2bf(acc[0][i][j][r] + bias2[0][j]);
#pragma unroll
    for (int e = 0; e < 4; ++e) {
        const int slot = e * 64 + L;
        const int row = slot >> 2, ch = slot & 3;
        const u32x4 v = *(const u32x4*)&scr[row * 36 + ch * 8];
        *(u32x4*)&Qh[((size_t)bh * 1024 + nb + row) * 64 + uh * 32 + ch * 8] = v;
    }

    // z=1: K frag-linear; token-major strip again
#pragma unroll
    for (int i = 0; i < 4; ++i)
#pragma unroll
        for (int j = 0; j < 2; ++j)
#pragma unroll
            for (int r = 0; r < 4; ++r)
                scr[(i * 16 + g * 4 + r) * 36 + j * 16 + c] =
                    f2bf(acc[1][i][j][r] + bias2[1][j]);
#pragma unroll
    for (int tau = 0; tau < 4; ++tau) {
        const u32x4 v = *(const u32x4*)&scr[(tau * 16 + c) * 36 + g * 8];
        *(u32x4*)&Kl[(((size_t)bh * 64 + (nb >> 4) + tau) * 2 + uh) * 512
                     + (size_t)L * 8] = v;
    }

    // z=2: V frag-linear; hd-major strip [32][68]
#pragma unroll
    for (int i = 0; i < 4; ++i)
#pragma unroll
        for (int j = 0; j < 2; ++j)
#pragma unroll
            for (int r = 0; r < 4; ++r)
                scr[(j * 16 + c) * 68 + i * 16 + g * 4 + r] =
                    f2bf(acc[2][i][j][r] + bias2[2][j]);
    const int T = nb >> 6;
#pragma unroll
    for (int t = 0; t < 4; ++t) {
        const int htl = t >> 1, u = t & 1;
        const u32x4 v = *(const u32x4*)&scr[(htl * 16 + c) * 68 + u * 32 + g * 8];
        *(u32x4*)&Vl[((((size_t)bh * 4 + uh * 2 + htl) * 16 + T) * 2 + u) * 512
                     + (size_t)L * 8] = v;
    }
}

// ---------------------------------------------------------------------------
// Out-proj GEMM retiled: 64m x 128n per block, grid 6x128 = 768 = 3/CU exact.
// 4 waves, each 64x32 (acc[4][2]). A staged once + W (2 GLL16/thr) per step.
// ---------------------------------------------------------------------------
__global__ __launch_bounds__(256, 3)
void gemm_outp(const ushort_t* __restrict__ attnb, const ushort_t* __restrict__ wob,
               const float* __restrict__ bo, float* __restrict__ out)
{
    __shared__ ushort_t smem[6144];      // As 2048 | Ws 4096
    ushort_t* As = smem;
    ushort_t* Ws = smem + 2048;
    const int tid = threadIdx.x, L = tid & 63, wv = tid >> 6;
    const int c = L & 15, g = L >> 4;
    const int n0 = blockIdx.x * 128, m0 = blockIdx.y * 64;
    const int qs = ((tid & 3) ^ ((tid >> 3) & 3)) * 8;
    const ushort_t* ap = attnb + (size_t)(m0 + (tid >> 2)) * 768 + qs;
    const ushort_t* wp = wob   + (size_t)(n0 + (tid >> 2)) * 768 + qs;
    const size_t st64 = (size_t)64 * 768;
    const int sg = (g ^ ((c >> 1) & 3)) * 8;

    f32x4 acc[4][2];
#pragma unroll
    for (int i = 0; i < 4; ++i)
#pragma unroll
        for (int j = 0; j < 2; ++j) acc[i][j] = (f32x4){0.f, 0.f, 0.f, 0.f};

    for (int k0 = 0; k0 < 768; k0 += 32) {
        __syncthreads();
        GLL16(ap + k0,        &As[(size_t)tid * 8]);
        GLL16(wp + k0,        &Ws[(size_t)tid * 8]);
        GLL16(wp + st64 + k0, &Ws[(size_t)(tid + 256) * 8]);
        __syncthreads();
        bf16x8 af[4], bf[2];
#pragma unroll
        for (int i = 0; i < 4; ++i)
            af[i] = *(const bf16x8*)&As[(i * 16 + c) * 32 + sg];
#pragma unroll
        for (int j = 0; j < 2; ++j)
            bf[j] = *(const bf16x8*)&Ws[(wv * 32 + j * 16 + c) * 32 + sg];
#pragma unroll
        for (int i = 0; i < 4; ++i)
#pragma unroll
            for (int j = 0; j < 2; ++j)
                acc[i][j] = __builtin_amdgcn_mfma_f32_16x16x32_bf16(
                    af[i], bf[j], acc[i][j], 0, 0, 0);
    }

#pragma unroll
    for (int i = 0; i < 4; ++i) {
        const int row = m0 + i * 16 + g * 4;
#pragma unroll
        for (int j = 0; j < 2; ++j) {
            const int col = n0 + wv * 32 + j * 16 + c;
            const float bsvo = bo[col];
#pragma unroll
            for (int r = 0; r < 4; ++r)
                out[(size_t)(row + r) * 768 + col] = acc[i][j][r] + bsvo;
        }
    }
}

// ---------------------------------------------------------------------------
// Flash: S^T = K.Q^T, fixed-max softmax (m=0), 1 wave/block, 32 q-rows.
// T-loop unrolled x2 with parity P-strips: iteration T+1's strip writes don't
// alias T's strip reads -> cross-iteration overlap. Grid (96 bh, 32 qtile).
// ---------------------------------------------------------------------------
__global__ __launch_bounds__(64, 3)
void flash_bf16(const ushort_t* __restrict__ Q, const ushort_t* __restrict__ Kl,
                const ushort_t* __restrict__ Vl, ushort_t* __restrict__ attnb)
{
    __shared__ ushort_t Ps[2][2][16 * 68];     // [parity][qgroup]
    const int L = threadIdx.x;                 // 0..63
    const int c = L & 15, g = L >> 4;
    const int bh = blockIdx.x, q0 = blockIdx.y * 32;
    const float SC2 = 0.05205954985329743f;    // 768^-0.5 * log2(e)

    const ushort_t* Qp = Q + ((size_t)bh * 1024 + q0 + c) * 64 + g * 8;
    bf16x8 qf[2][2];
    qf[0][0] = *(const bf16x8*)Qp;
    qf[0][1] = *(const bf16x8*)(Qp + 32);
    qf[1][0] = *(const bf16x8*)(Qp + 16 * 64);
    qf[1][1] = *(const bf16x8*)(Qp + 16 * 64 + 32);

    const ushort_t* Kb = Kl + (size_t)bh * 65536 + (size_t)L * 8;
    const ushort_t* Vb = Vl + (size_t)bh * 65536 + (size_t)L * 8;

    f32x4 o[2][4];
#pragma unroll
    for (int w = 0; w < 2; ++w)
#pragma unroll
        for (int ht = 0; ht < 4; ++ht) o[w][ht] = (f32x4){0.f, 0.f, 0.f, 0.f};
    float ls[2] = {0.f, 0.f};

    bf16x8 kf0[4], kf1[4];
#pragma unroll
    for (int ct = 0; ct < 4; ++ct) {
        kf0[ct] = *(const bf16x8*)(Kb + (size_t)(ct * 2 + 0) * 512);
        kf1[ct] = *(const bf16x8*)(Kb + (size_t)(ct * 2 + 1) * 512);
    }

    for (int T0 = 0; T0 < 16; T0 += 2) {
#pragma unroll
        for (int p = 0; p < 2; ++p) {
            const int T = T0 + p;
            // V frags (issued early; used after softmax)
            bf16x8 vf0[4], vf1[4];
#pragma unroll
            for (int ht = 0; ht < 4; ++ht) {
                const ushort_t* vp = Vb + (size_t)((ht * 16 + T) * 2) * 512;
                vf0[ht] = *(const bf16x8*)vp;
                vf1[ht] = *(const bf16x8*)(vp + 512);
            }
            // S^T for both q-groups
            f32x4 s[2][4];
#pragma unroll
            for (int w = 0; w < 2; ++w)
#pragma unroll
                for (int ct = 0; ct < 4; ++ct) {
                    f32x4 zz = (f32x4){0.f, 0.f, 0.f, 0.f};
                    zz = __builtin_amdgcn_mfma_f32_16x16x32_bf16(kf0[ct], qf[w][0], zz, 0, 0, 0);
                    zz = __builtin_amdgcn_mfma_f32_16x16x32_bf16(kf1[ct], qf[w][1], zz, 0, 0, 0);
                    s[w][ct] = zz;
                }
            // in-place K prefetch for next T
            const int Tn = (T < 15) ? T + 1 : 15;
#pragma unroll
            for (int ct = 0; ct < 4; ++ct) {
                const ushort_t* kp = Kb + (size_t)((Tn * 4 + ct) * 2) * 512;
                kf0[ct] = *(const bf16x8*)kp;
                kf1[ct] = *(const bf16x8*)(kp + 512);
            }
            // fixed-max softmax -> parity strip
#pragma unroll
            for (int w = 0; w < 2; ++w) {
#pragma unroll
                for (int ct = 0; ct < 4; ++ct) {
                    float pv[4];
#pragma unroll
                    for (int r = 0; r < 4; ++r)
                        pv[r] = __builtin_amdgcn_exp2f(s[w][ct][r] * SC2);
                    ls[w] += (pv[0] + pv[1]) + (pv[2] + pv[3]);
                    const unsigned w01 = __builtin_amdgcn_perm(
                        __float_as_uint(pv[1]), __float_as_uint(pv[0]), 0x07060302u);
                    const unsigned w23 = __builtin_amdgcn_perm(
                        __float_as_uint(pv[3]), __float_as_uint(pv[2]), 0x07060302u);
                    *(u32x2*)&Ps[p][w][c * 68 + ct * 16 + g * 4] = (u32x2){w01, w23};
                }
            }
            // P^T as B-frags; O^T += V^T . P^T
#pragma unroll
            for (int w = 0; w < 2; ++w) {
                const int pb = c * 68 + g * 8;
                const u32x4 pa  = *(const u32x4*)&Ps[p][w][pb];
                const u32x4 pbv = *(const u32x4*)&Ps[p][w][pb + 32];
                const bf16x8 pf0 = __builtin_bit_cast(bf16x8, pa);
                const bf16x8 pf1 = __builtin_bit_cast(bf16x8, pbv);
#pragma unroll
                for (int ht = 0; ht < 4; ++ht) {
                    o[w][ht] = __builtin_amdgcn_mfma_f32_16x16x32_bf16(vf0[ht], pf0, o[w][ht], 0, 0, 0);
                    o[w][ht] = __builtin_amdgcn_mfma_f32_16x16x32_bf16(vf1[ht], pf1, o[w][ht], 0, 0, 0);
                }
            }
        }
    }

    const int b = bh / 12, h = bh % 12;
#pragma unroll
    for (int w = 0; w < 2; ++w) {
        float l = ls[w];
        l += __shfl_xor(l, 16);
        l += __shfl_xor(l, 32);
        const float inv = 1.f / l;
#pragma unroll
        for (int ht = 0; ht < 4; ++ht) {
            const unsigned w0 = pk16(f2bf(o[w][ht][0] * inv), f2bf(o[w][ht][1] * inv));
            const unsigned w1 = pk16(f2bf(o[w][ht][2] * inv), f2bf(o[w][ht][3] * inv));
            *(u32x2*)&Ps[0][w][c * 68 + ht * 16 + g * 4] = (u32x2){w0, w1};
        }
#pragma unroll
        for (int e = 0; e < 2; ++e) {
            const int row = e * 8 + (L >> 3);
            const int ch  = L & 7;
            const int si  = row * 68 + ch * 8;
            const u32x2 t0 = *(const u32x2*)&Ps[0][w][si];
            const u32x2 t1 = *(const u32x2*)&Ps[0][w][si + 4];
            *(u32x4*)&attnb[((size_t)(b * 1024 + q0 + w * 16 + row)) * 768 + h * 64 + ch * 8]
                = (u32x4){t0.x, t0.y, t1.x, t1.y};
        }
    }
}

extern "C" void kernel_launch(void* const* d_in, const int* in_sizes, int n_in,
                              void* d_out, int out_size, void* d_ws, size_t ws_size,
                              hipStream_t stream)
{
    const float* x  = (const float*)d_in[0];
    const float* Wq = (const float*)d_in[1];
    const float* bq = (const float*)d_in[2];
    const float* Wk = (const float*)d_in[3];
    const float* bk = (const float*)d_in[4];
    const float* Wv = (const float*)d_in[5];
    const float* bv = (const float*)d_in[6];
    const float* Wo = (const float*)d_in[7];
    const float* bo = (const float*)d_in[8];
    float* out = (float*)d_out;

    char* ws = (char*)d_ws;
    ushort_t* xb    = (ushort_t*)(ws);
    ushort_t* wqb   = (ushort_t*)(ws + 12582912);
    ushort_t* wkb   = (ushort_t*)(ws + 12582912 + 1179648);
    ushort_t* wvb   = (ushort_t*)(ws + 12582912 + 2359296);
    ushort_t* wob   = (ushort_t*)(ws + 12582912 + 3538944);
    ushort_t* Qh    = (ushort_t*)(ws + 17301504);
    ushort_t* Kl    = (ushort_t*)(ws + 29884416);
    ushort_t* Vl    = (ushort_t*)(ws + 42467328);
    ushort_t* attnb = (ushort_t*)(ws + 55050240);

    cast_all<<<dim3(3072, 5), 256, 0, stream>>>(x, Wq, Wk, Wv, Wo,
                                                xb, wqb, wkb, wvb, wob);
    gemm_qkv<<<dim3(6, 128), 256, 0, stream>>>(xb, wqb, wkb, wvb,
                                               bq, bk, bv, Qh, Kl, Vl);
    flash_bf16<<<dim3(96, 32), 64, 0, stream>>>(Qh, Kl, Vl, attnb);
    gemm_outp<<<dim3(6, 128), 256, 0, stream>>>(attnb, wob, bo, out);
}

// Round 12
// 187.962 us; speedup vs baseline: 1.0523x; 1.0523x over previous
//
#include <hip/hip_runtime.h>
#include <math.h>

// Round 12: W never touches LDS. cast_all pre-swizzles all four weight
// matrices into B-frag-linear layout (W'[t16][kb][lane][8]); the GEMM
// K-loops stage ONLY the shared A-tile via global_load_lds (1 per thread,
// 2KB/block) and load W-frags directly global->VGPR as coalesced 1KB
// dwordx4 with flash-style in-place prefetch. Rationale: W has zero
// cross-wave reuse in-block, and regular global loads pipeline ACROSS
// s_barrier (no vmcnt(0) drain), unlike the global_load_lds queue.

typedef __bf16 bf16x8 __attribute__((ext_vector_type(8)));
typedef float  f32x4  __attribute__((ext_vector_type(4)));
typedef unsigned u32x2 __attribute__((ext_vector_type(2)));
typedef unsigned u32x4 __attribute__((ext_vector_type(4)));
typedef unsigned short ushort_t;

__device__ __forceinline__ unsigned short f2bf(float f) {
    unsigned u = __float_as_uint(f);
    u += 0x7fffu + ((u >> 16) & 1u);          // round-to-nearest-even
    return (unsigned short)(u >> 16);
}
__device__ __forceinline__ unsigned pk16(unsigned short lo, unsigned short hi) {
    return (unsigned)lo | ((unsigned)hi << 16);
}

#define GLL16(g, l)                                                                        \
    __builtin_amdgcn_global_load_lds((const __attribute__((address_space(1))) void*)(g),   \
                                     (__attribute__((address_space(3))) void*)(l), 16, 0, 0)

// ---------------------------------------------------------------------------
// cast: y=0 -> x row-major bf16 (3072 blocks). y=1..4 -> W frag-linear:
// tile (t,kb) holds W[t*16+c][kb*32 + g*8 .. +7] at ((t*24+kb)*64 + L)*8.
// ---------------------------------------------------------------------------
__global__ __launch_bounds__(256)
void cast_all(const float* __restrict__ x,
              const float* __restrict__ w0, const float* __restrict__ w1,
              const float* __restrict__ w2, const float* __restrict__ w3,
              ushort_t* __restrict__ xb, ushort_t* __restrict__ wb0,
              ushort_t* __restrict__ wb1, ushort_t* __restrict__ wb2,
              ushort_t* __restrict__ wb3)
{
    const int y = blockIdx.y;
    if (y == 0) {
        const int i = (blockIdx.x * 256 + threadIdx.x) * 8;   // 8192*768 exact
        const float4 f0 = *(const float4*)(x + i);
        const float4 f1 = *(const float4*)(x + i + 4);
        ushort4 p0, p1;
        p0.x = f2bf(f0.x); p0.y = f2bf(f0.y); p0.z = f2bf(f0.z); p0.w = f2bf(f0.w);
        p1.x = f2bf(f1.x); p1.y = f2bf(f1.y); p1.z = f2bf(f1.z); p1.w = f2bf(f1.w);
        *(ushort4*)(xb + i)     = p0;
        *(ushort4*)(xb + i + 4) = p1;
        return;
    }
    const int tile = blockIdx.x * 4 + (threadIdx.x >> 6);
    if (tile >= 48 * 24) return;                      // 1152 tiles per weight
    const float* s; ushort_t* d;
    switch (y) {
        case 1:  s = w0; d = wb0; break;
        case 2:  s = w1; d = wb1; break;
        case 3:  s = w2; d = wb2; break;
        default: s = w3; d = wb3; break;
    }
    const int t = tile / 24, kb = tile % 24;
    const int L = threadIdx.x & 63, c = L & 15, g = L >> 4;
    const float* sp = s + (size_t)(t * 16 + c) * 768 + kb * 32 + g * 8;
    const float4 f0 = *(const float4*)sp;
    const float4 f1 = *(const float4*)(sp + 4);
    ushort4 p0, p1;
    p0.x = f2bf(f0.x); p0.y = f2bf(f0.y); p0.z = f2bf(f0.z); p0.w = f2bf(f0.w);
    p1.x = f2bf(f1.x); p1.y = f2bf(f1.y); p1.z = f2bf(f1.z); p1.w = f2bf(f1.w);
    ushort_t* dp = d + ((size_t)tile * 64 + L) * 8;
    *(ushort4*)dp       = p0;
    *(ushort4*)(dp + 4) = p1;
}

// ---------------------------------------------------------------------------
// Z-fused QKV GEMM, A-only LDS. Block = 64m x 128n, 4 waves (64x32 per z).
// W-frags direct from frag-linear global (in-place prefetched).
// ---------------------------------------------------------------------------
__global__ __launch_bounds__(256, 3)
void gemm_qkv(const ushort_t* __restrict__ xb,
              const ushort_t* __restrict__ wqb, const ushort_t* __restrict__ wkb,
              const ushort_t* __restrict__ wvb,
              const float* __restrict__ bq, const float* __restrict__ bk,
              const float* __restrict__ bv,
              ushort_t* __restrict__ Qh, ushort_t* __restrict__ Kl,
              ushort_t* __restrict__ Vl)
{
    __shared__ ushort_t smem[9216];      // As 2048 | epilogue scratch 4x2304
    ushort_t* As = smem;

    const int tid = threadIdx.x, L = tid & 63, wv = tid >> 6;
    const int c = L & 15, g = L >> 4;
    const int n0 = blockIdx.x * 128, m0 = blockIdx.y * 64;

    const int qs = ((tid & 3) ^ ((tid >> 3) & 3)) * 8;   // swizzled k-chunk
    const ushort_t* ap = xb + (size_t)(m0 + (tid >> 2)) * 768 + qs;
    const int sg = (g ^ ((c >> 1) & 3)) * 8;             // swizzled read col

    // frag-linear W bases: tile t = bx*8 + wv*2 + j, offset ((t*24+kb)*64+L)*8
    const size_t wbase = ((size_t)(blockIdx.x * 8 + wv * 2) * 24 * 64 + L) * 8;
    const ushort_t* wqp = wqb + wbase;
    const ushort_t* wkp = wkb + wbase;
    const ushort_t* wvp = wvb + wbase;
    // j stride = 24*64*8 = 12288 shorts; kb stride = 512 shorts

    f32x4 acc[3][4][2];
#pragma unroll
    for (int z = 0; z < 3; ++z)
#pragma unroll
        for (int i = 0; i < 4; ++i)
#pragma unroll
            for (int j = 0; j < 2; ++j) acc[z][i][j] = (f32x4){0.f, 0.f, 0.f, 0.f};

    bf16x8 wf[3][2];
#pragma unroll
    for (int j = 0; j < 2; ++j) {
        wf[0][j] = *(const bf16x8*)(wqp + j * 12288);
        wf[1][j] = *(const bf16x8*)(wkp + j * 12288);
        wf[2][j] = *(const bf16x8*)(wvp + j * 12288);
    }

    for (int kb = 0; kb < 24; ++kb) {
        __syncthreads();
        GLL16(ap + kb * 32, &As[(size_t)tid * 8]);
        __syncthreads();
        bf16x8 af[4];
#pragma unroll
        for (int i = 0; i < 4; ++i)
            af[i] = *(const bf16x8*)&As[(i * 16 + c) * 32 + sg];
#pragma unroll
        for (int z = 0; z < 3; ++z)
#pragma unroll
            for (int i = 0; i < 4; ++i)
#pragma unroll
                for (int j = 0; j < 2; ++j)
                    acc[z][i][j] = __builtin_amdgcn_mfma_f32_16x16x32_bf16(
                        af[i], wf[z][j], acc[z][i][j], 0, 0, 0);
        // in-place prefetch next kb (regular global loads: no barrier drain)
        const int kn = (kb < 23) ? kb + 1 : 23;
#pragma unroll
        for (int j = 0; j < 2; ++j) {
            wf[0][j] = *(const bf16x8*)(wqp + j * 12288 + kn * 512);
            wf[1][j] = *(const bf16x8*)(wkp + j * 12288 + kn * 512);
            wf[2][j] = *(const bf16x8*)(wvp + j * 12288 + kn * 512);
        }
    }

    // ---------------- epilogues (per-wave private strips) ----------------
    const int b  = m0 >> 10, nb = m0 & 1023;
    const int hcol = n0 + wv * 32;
    const int h = hcol >> 6, uh = (hcol >> 5) & 1;
    const int bh = b * 12 + h;
    ushort_t* scr = smem + wv * 2304;

    float bias2[3][2];
#pragma unroll
    for (int j = 0; j < 2; ++j) {
        bias2[0][j] = bq[hcol + j * 16 + c];
        bias2[1][j] = bk[hcol + j * 16 + c];
        bias2[2][j] = bv[hcol + j * 16 + c];
    }

    __syncthreads();   // staging LDS -> scratch

    // z=0: Q plain [bh][token][hd64]; token-major strip [64][36]
#pragma unroll
    for (int i = 0; i < 4; ++i)
#pragma unroll
        for (int j = 0; j < 2; ++j)
#pragma unroll
            for (int r = 0; r < 4; ++r)
                scr[(i * 16 + g * 4 + r) * 36 + j * 16 + c] =
                    f2bf(acc[0][i][j][r] + bias2[0][j]);
#pragma unroll
    for (int e = 0; e < 4; ++e) {
        const int slot = e * 64 + L;
        const int row = slot >> 2, ch = slot & 3;
        const u32x4 v = *(const u32x4*)&scr[row * 36 + ch * 8];
        *(u32x4*)&Qh[((size_t)bh * 1024 + nb + row) * 64 + uh * 32 + ch * 8] = v;
    }

    // z=1: K frag-linear; token-major strip again
#pragma unroll
    for (int i = 0; i < 4; ++i)
#pragma unroll
        for (int j = 0; j < 2; ++j)
#pragma unroll
            for (int r = 0; r < 4; ++r)
                scr[(i * 16 + g * 4 + r) * 36 + j * 16 + c] =
                    f2bf(acc[1][i][j][r] + bias2[1][j]);
#pragma unroll
    for (int tau = 0; tau < 4; ++tau) {
        const u32x4 v = *(const u32x4*)&scr[(tau * 16 + c) * 36 + g * 8];
        *(u32x4*)&Kl[(((size_t)bh * 64 + (nb >> 4) + tau) * 2 + uh) * 512
                     + (size_t)L * 8] = v;
    }

    // z=2: V frag-linear; hd-major strip [32][68]
#pragma unroll
    for (int i = 0; i < 4; ++i)
#pragma unroll
        for (int j = 0; j < 2; ++j)
#pragma unroll
            for (int r = 0; r < 4; ++r)
                scr[(j * 16 + c) * 68 + i * 16 + g * 4 + r] =
                    f2bf(acc[2][i][j][r] + bias2[2][j]);
    const int T = nb >> 6;
#pragma unroll
    for (int t = 0; t < 4; ++t) {
        const int htl = t >> 1, u = t & 1;
        const u32x4 v = *(const u32x4*)&scr[(htl * 16 + c) * 68 + u * 32 + g * 8];
        *(u32x4*)&Vl[((((size_t)bh * 4 + uh * 2 + htl) * 16 + T) * 2 + u) * 512
                     + (size_t)L * 8] = v;
    }
}

// ---------------------------------------------------------------------------
// Out-proj GEMM, A-only LDS: 64m x 128n, grid 6x128 = 768 = 3/CU exact.
// ---------------------------------------------------------------------------
__global__ __launch_bounds__(256, 3)
void gemm_outp(const ushort_t* __restrict__ attnb, const ushort_t* __restrict__ wob,
               const float* __restrict__ bo, float* __restrict__ out)
{
    __shared__ ushort_t smem[2048];      // As only
    ushort_t* As = smem;
    const int tid = threadIdx.x, L = tid & 63, wv = tid >> 6;
    const int c = L & 15, g = L >> 4;
    const int n0 = blockIdx.x * 128, m0 = blockIdx.y * 64;
    const int qs = ((tid & 3) ^ ((tid >> 3) & 3)) * 8;
    const ushort_t* ap = attnb + (size_t)(m0 + (tid >> 2)) * 768 + qs;
    const int sg = (g ^ ((c >> 1) & 3)) * 8;

    const size_t wbase = ((size_t)(blockIdx.x * 8 + wv * 2) * 24 * 64 + L) * 8;
    const ushort_t* wop = wob + wbase;

    f32x4 acc[4][2];
#pragma unroll
    for (int i = 0; i < 4; ++i)
#pragma unroll
        for (int j = 0; j < 2; ++j) acc[i][j] = (f32x4){0.f, 0.f, 0.f, 0.f};

    bf16x8 wf[2];
#pragma unroll
    for (int j = 0; j < 2; ++j) wf[j] = *(const bf16x8*)(wop + j * 12288);

    for (int kb = 0; kb < 24; ++kb) {
        __syncthreads();
        GLL16(ap + kb * 32, &As[(size_t)tid * 8]);
        __syncthreads();
        bf16x8 af[4];
#pragma unroll
        for (int i = 0; i < 4; ++i)
            af[i] = *(const bf16x8*)&As[(i * 16 + c) * 32 + sg];
#pragma unroll
        for (int i = 0; i < 4; ++i)
#pragma unroll
            for (int j = 0; j < 2; ++j)
                acc[i][j] = __builtin_amdgcn_mfma_f32_16x16x32_bf16(
                    af[i], wf[j], acc[i][j], 0, 0, 0);
        const int kn = (kb < 23) ? kb + 1 : 23;
#pragma unroll
        for (int j = 0; j < 2; ++j)
            wf[j] = *(const bf16x8*)(wop + j * 12288 + kn * 512);
    }

#pragma unroll
    for (int i = 0; i < 4; ++i) {
        const int row = m0 + i * 16 + g * 4;
#pragma unroll
        for (int j = 0; j < 2; ++j) {
            const int col = n0 + wv * 32 + j * 16 + c;
            const float bsvo = bo[col];
#pragma unroll
            for (int r = 0; r < 4; ++r)
                out[(size_t)(row + r) * 768 + col] = acc[i][j][r] + bsvo;
        }
    }
}

// ---------------------------------------------------------------------------
// Flash (R11): S^T = K.Q^T, fixed-max softmax, 1 wave/block, 32 q-rows,
// parity P-strips, in-place K prefetch, bare v_exp_f32. Grid (96 bh, 32 qt).
// ---------------------------------------------------------------------------
__global__ __launch_bounds__(64, 3)
void flash_bf16(const ushort_t* __restrict__ Q, const ushort_t* __restrict__ Kl,
                const ushort_t* __restrict__ Vl, ushort_t* __restrict__ attnb)
{
    __shared__ ushort_t Ps[2][2][16 * 68];     // [parity][qgroup]
    const int L = threadIdx.x;                 // 0..63
    const int c = L & 15, g = L >> 4;
    const int bh = blockIdx.x, q0 = blockIdx.y * 32;
    const float SC2 = 0.05205954985329743f;    // 768^-0.5 * log2(e)

    const ushort_t* Qp = Q + ((size_t)bh * 1024 + q0 + c) * 64 + g * 8;
    bf16x8 qf[2][2];
    qf[0][0] = *(const bf16x8*)Qp;
    qf[0][1] = *(const bf16x8*)(Qp + 32);
    qf[1][0] = *(const bf16x8*)(Qp + 16 * 64);
    qf[1][1] = *(const bf16x8*)(Qp + 16 * 64 + 32);

    const ushort_t* Kb = Kl + (size_t)bh * 65536 + (size_t)L * 8;
    const ushort_t* Vb = Vl + (size_t)bh * 65536 + (size_t)L * 8;

    f32x4 o[2][4];
#pragma unroll
    for (int w = 0; w < 2; ++w)
#pragma unroll
        for (int ht = 0; ht < 4; ++ht) o[w][ht] = (f32x4){0.f, 0.f, 0.f, 0.f};
    float ls[2] = {0.f, 0.f};

    bf16x8 kf0[4], kf1[4];
#pragma unroll
    for (int ct = 0; ct < 4; ++ct) {
        kf0[ct] = *(const bf16x8*)(Kb + (size_t)(ct * 2 + 0) * 512);
        kf1[ct] = *(const bf16x8*)(Kb + (size_t)(ct * 2 + 1) * 512);
    }

    for (int T0 = 0; T0 < 16; T0 += 2) {
#pragma unroll
        for (int p = 0; p < 2; ++p) {
            const int T = T0 + p;
            bf16x8 vf0[4], vf1[4];
#pragma unroll
            for (int ht = 0; ht < 4; ++ht) {
                const ushort_t* vp = Vb + (size_t)((ht * 16 + T) * 2) * 512;
                vf0[ht] = *(const bf16x8*)vp;
                vf1[ht] = *(const bf16x8*)(vp + 512);
            }
            f32x4 s[2][4];
#pragma unroll
            for (int w = 0; w < 2; ++w)
#pragma unroll
                for (int ct = 0; ct < 4; ++ct) {
                    f32x4 zz = (f32x4){0.f, 0.f, 0.f, 0.f};
                    zz = __builtin_amdgcn_mfma_f32_16x16x32_bf16(kf0[ct], qf[w][0], zz, 0, 0, 0);
                    zz = __builtin_amdgcn_mfma_f32_16x16x32_bf16(kf1[ct], qf[w][1], zz, 0, 0, 0);
                    s[w][ct] = zz;
                }
            const int Tn = (T < 15) ? T + 1 : 15;
#pragma unroll
            for (int ct = 0; ct < 4; ++ct) {
                const ushort_t* kp = Kb + (size_t)((Tn * 4 + ct) * 2) * 512;
                kf0[ct] = *(const bf16x8*)kp;
                kf1[ct] = *(const bf16x8*)(kp + 512);
            }
#pragma unroll
            for (int w = 0; w < 2; ++w) {
#pragma unroll
                for (int ct = 0; ct < 4; ++ct) {
                    float pv[4];
#pragma unroll
                    for (int r = 0; r < 4; ++r)
                        pv[r] = __builtin_amdgcn_exp2f(s[w][ct][r] * SC2);
                    ls[w] += (pv[0] + pv[1]) + (pv[2] + pv[3]);
                    const unsigned w01 = __builtin_amdgcn_perm(
                        __float_as_uint(pv[1]), __float_as_uint(pv[0]), 0x07060302u);
                    const unsigned w23 = __builtin_amdgcn_perm(
                        __float_as_uint(pv[3]), __float_as_uint(pv[2]), 0x07060302u);
                    *(u32x2*)&Ps[p][w][c * 68 + ct * 16 + g * 4] = (u32x2){w01, w23};
                }
            }
#pragma unroll
            for (int w = 0; w < 2; ++w) {
                const int pb = c * 68 + g * 8;
                const u32x4 pa  = *(const u32x4*)&Ps[p][w][pb];
                const u32x4 pbv = *(const u32x4*)&Ps[p][w][pb + 32];
                const bf16x8 pf0 = __builtin_bit_cast(bf16x8, pa);
                const bf16x8 pf1 = __builtin_bit_cast(bf16x8, pbv);
#pragma unroll
                for (int ht = 0; ht < 4; ++ht) {
                    o[w][ht] = __builtin_amdgcn_mfma_f32_16x16x32_bf16(vf0[ht], pf0, o[w][ht], 0, 0, 0);
                    o[w][ht] = __builtin_amdgcn_mfma_f32_16x16x32_bf16(vf1[ht], pf1, o[w][ht], 0, 0, 0);
                }
            }
        }
    }

    const int b = bh / 12, h = bh % 12;
#pragma unroll
    for (int w = 0; w < 2; ++w) {
        float l = ls[w];
        l += __shfl_xor(l, 16);
        l += __shfl_xor(l, 32);
        const float inv = 1.f / l;
#pragma unroll
        for (int ht = 0; ht < 4; ++ht) {
            const unsigned w0 = pk16(f2bf(o[w][ht][0] * inv), f2bf(o[w][ht][1] * inv));
            const unsigned w1 = pk16(f2bf(o[w][ht][2] * inv), f2bf(o[w][ht][3] * inv));
            *(u32x2*)&Ps[0][w][c * 68 + ht * 16 + g * 4] = (u32x2){w0, w1};
        }
#pragma unroll
        for (int e = 0; e < 2; ++e) {
            const int row = e * 8 + (L >> 3);
            const int ch  = L & 7;
            const int si  = row * 68 + ch * 8;
            const u32x2 t0 = *(const u32x2*)&Ps[0][w][si];
            const u32x2 t1 = *(const u32x2*)&Ps[0][w][si + 4];
            *(u32x4*)&attnb[((size_t)(b * 1024 + q0 + w * 16 + row)) * 768 + h * 64 + ch * 8]
                = (u32x4){t0.x, t0.y, t1.x, t1.y};
        }
    }
}

extern "C" void kernel_launch(void* const* d_in, const int* in_sizes, int n_in,
                              void* d_out, int out_size, void* d_ws, size_t ws_size,
                              hipStream_t stream)
{
    const float* x  = (const float*)d_in[0];
    const float* Wq = (const float*)d_in[1];
    const float* bq = (const float*)d_in[2];
    const float* Wk = (const float*)d_in[3];
    const float* bk = (const float*)d_in[4];
    const float* Wv = (const float*)d_in[5];
    const float* bv = (const float*)d_in[6];
    const float* Wo = (const float*)d_in[7];
    const float* bo = (const float*)d_in[8];
    float* out = (float*)d_out;

    char* ws = (char*)d_ws;
    ushort_t* xb    = (ushort_t*)(ws);
    ushort_t* wqb   = (ushort_t*)(ws + 12582912);
    ushort_t* wkb   = (ushort_t*)(ws + 12582912 + 1179648);
    ushort_t* wvb   = (ushort_t*)(ws + 12582912 + 2359296);
    ushort_t* wob   = (ushort_t*)(ws + 12582912 + 3538944);
    ushort_t* Qh    = (ushort_t*)(ws + 17301504);
    ushort_t* Kl    = (ushort_t*)(ws + 29884416);
    ushort_t* Vl    = (ushort_t*)(ws + 42467328);
    ushort_t* attnb = (ushort_t*)(ws + 55050240);

    cast_all<<<dim3(3072, 5), 256, 0, stream>>>(x, Wq, Wk, Wv, Wo,
                                                xb, wqb, wkb, wvb, wob);
    gemm_qkv<<<dim3(6, 128), 256, 0, stream>>>(xb, wqb, wkb, wvb,
                                               bq, bk, bv, Qh, Kl, Vl);
    flash_bf16<<<dim3(96, 32), 64, 0, stream>>>(Qh, Kl, Vl, attnb);
    gemm_outp<<<dim3(6, 128), 256, 0, stream>>>(attnb, wob, bo, out);
}